// Round 10
// baseline (663.791 us; speedup 1.0000x reference)
//
#include <hip/hip_runtime.h>

#define SCALE 10.0f           // 1 / TEMPERATURE
#define EPS_MARGIN 0.011f     // bf16-dot err (0.008) + u16 round-up/trunc slack
#define PAIR_CAP 32768

typedef __attribute__((ext_vector_type(8))) short short8;
typedef __attribute__((ext_vector_type(4))) float floatx4;

#define MFMA16(a, b, c) __builtin_amdgcn_mfma_f32_16x16x32_bf16((a), (b), (c), 0, 0, 0)

// ---------- helpers ----------
__device__ __forceinline__ unsigned int ordered_bits(float f) {
    unsigned int b = __float_as_uint(f);
    return (b & 0x80000000u) ? ~b : (b | 0x80000000u);
}
__device__ __forceinline__ float from_ordered(unsigned int u) {
    return __uint_as_float((u & 0x80000000u) ? (u ^ 0x80000000u) : ~u);
}
__device__ __forceinline__ short bf_rne(float x) {   // fp32 -> bf16 bits, RNE
    unsigned int u = __float_as_uint(x);
    return (short)((u + 0x7FFFu + ((u >> 16) & 1u)) >> 16);
}

// ---------- K1: l2-normalize p1,p2 -> pn fp32 + pnb bf16; init state --------
__global__ void k_prep(const float* __restrict__ p1, const float* __restrict__ p2,
                       float* __restrict__ pn, short* __restrict__ pnb,
                       unsigned long long* __restrict__ best,
                       unsigned int* __restrict__ paircnt, float* __restrict__ sums) {
    int row = blockIdx.x;               // 0..4095
    int t = threadIdx.x;                // 0..63
    const float* src = (row < 2048) ? (p1 + (size_t)row * 128)
                                    : (p2 + (size_t)(row - 2048) * 128);
    float2 v = ((const float2*)src)[t];
    float ss = v.x * v.x + v.y * v.y;
    #pragma unroll
    for (int o = 32; o; o >>= 1) ss += __shfl_xor(ss, o);
    float inv = 1.0f / sqrtf(ss);
    float2 o2; o2.x = v.x * inv; o2.y = v.y * inv;
    ((float2*)(pn + (size_t)row * 128))[t] = o2;
    unsigned int pk = (unsigned int)(unsigned short)bf_rne(o2.x)
                    | ((unsigned int)(unsigned short)bf_rne(o2.y) << 16);
    ((unsigned int*)(pnb + (size_t)row * 128))[t] = pk;
    if (t == 0) { best[row] = 0ULL; if (row == 0) *paircnt = 0u; }
    if (row < 128) sums[row * 64 + t] = 0.0f;
}

// ---------- K2: queue fp32 -> qb bf16 ----------
__global__ void k_qcvt(const float* __restrict__ queue, short* __restrict__ qb) {
    size_t i = ((size_t)blockIdx.x * 256 + threadIdx.x) * 8;
    float4 f0 = *(const float4*)(queue + i);
    float4 f1 = *(const float4*)(queue + i + 4);
    short8 o;
    o[0] = bf_rne(f0.x); o[1] = bf_rne(f0.y); o[2] = bf_rne(f0.z); o[3] = bf_rne(f0.w);
    o[4] = bf_rne(f1.x); o[5] = bf_rne(f1.y); o[6] = bf_rne(f1.z); o[7] = bf_rne(f1.w);
    *(short8*)(qb + i) = o;
}

// ---------- 16-q tile: 2 rf frags, k-outer ----------
__device__ __forceinline__ void tile2(const short8 A[2][4],
                                      short8 b0, short8 b1, short8 b2, short8 b3,
                                      float rmaxc[2][4]) {
    floatx4 acc[2];
    floatx4 zero = {0.0f, 0.0f, 0.0f, 0.0f};
    acc[0] = MFMA16(A[0][0], b0, zero); acc[1] = MFMA16(A[1][0], b0, zero);
    acc[0] = MFMA16(A[0][1], b1, acc[0]); acc[1] = MFMA16(A[1][1], b1, acc[1]);
    acc[0] = MFMA16(A[0][2], b2, acc[0]); acc[1] = MFMA16(A[1][2], b2, acc[1]);
    acc[0] = MFMA16(A[0][3], b3, acc[0]); acc[1] = MFMA16(A[1][3], b3, acc[1]);
    #pragma unroll
    for (int rf = 0; rf < 2; ++rf)
        #pragma unroll
        for (int r = 0; r < 4; ++r) rmaxc[rf][r] = fmaxf(rmaxc[rf][r], acc[rf][r]);
}

// ---------- K3: single MFMA screen -> per-(64q-chunk, row) max u16 -----------
// Wave owns 32 rows (A in 32 VGPRs) x 1024-q strip. Block = 4 waves = 128 rows.
// Grid 2048 = 32 rowblocks x 64 qsplits, XCD-swizzled (<=3 strips/XCD in L2).
// 3 waves/SIMD (launch_bounds 256,3): B-load latency hidden by occupancy.
// cm layout TRANSPOSED [chunk][row]: wave's 32 u16 stores are contiguous.
__global__ __launch_bounds__(256, 3) void k_screen(const short* __restrict__ pnb,
                                                   const short* __restrict__ qb,
                                                   unsigned short* __restrict__ cm) {
    int tid = threadIdx.x;
    int lane = tid & 63, wv = tid >> 6;
    int n16 = lane & 15, quad = lane >> 4;

    int id = blockIdx.x;                // 0..2047
    int xcd = id & 7;
    int g = id >> 3;                    // 0..255
    int rowblk = g & 31;                // 32 rowblocks of 128 rows
    int qsub = g >> 5;                  // 0..7
    int qsplit = xcd * 8 + qsub;        // 64 strips of 1024 q
    int rowbase = rowblk * 128 + wv * 32;
    int qstart = qsplit * 1024;

    short8 A[2][4];                     // 32 VGPRs
    #pragma unroll
    for (int rf = 0; rf < 2; ++rf) {
        const short* ap = pnb + (size_t)(rowbase + rf * 16 + n16) * 128 + quad * 8;
        #pragma unroll
        for (int kk = 0; kk < 4; ++kk)
            A[rf][kk] = *(const short8*)(ap + kk * 32);
    }

    float rmaxc[2][4];
    #pragma unroll
    for (int rf = 0; rf < 2; ++rf)
        #pragma unroll
        for (int r = 0; r < 4; ++r) rmaxc[rf][r] = -1e30f;

    const short* lp = qb + (size_t)(qstart + n16) * 128 + quad * 8;
    short8 a0 = *(const short8*)(lp), a1 = *(const short8*)(lp + 32),
           a2 = *(const short8*)(lp + 64), a3 = *(const short8*)(lp + 96);

    for (int c = 0; c < 16; ++c) {      // 16 chunks of 64 q (4 tiles each)
        const short* p1p = lp + 2048;
        short8 b0 = *(const short8*)(p1p), b1 = *(const short8*)(p1p + 32),
               b2 = *(const short8*)(p1p + 64), b3 = *(const short8*)(p1p + 96);
        tile2(A, a0, a1, a2, a3, rmaxc);
        const short* p2p = lp + 4096;
        a0 = *(const short8*)(p2p); a1 = *(const short8*)(p2p + 32);
        a2 = *(const short8*)(p2p + 64); a3 = *(const short8*)(p2p + 96);
        tile2(A, b0, b1, b2, b3, rmaxc);
        const short* p3p = lp + 6144;
        b0 = *(const short8*)(p3p); b1 = *(const short8*)(p3p + 32);
        b2 = *(const short8*)(p3p + 64); b3 = *(const short8*)(p3p + 96);
        tile2(A, a0, a1, a2, a3, rmaxc);
        const short* p4p = lp + 8192;   // last chunk over-reads into pnb (safe)
        a0 = *(const short8*)(p4p); a1 = *(const short8*)(p4p + 32);
        a2 = *(const short8*)(p4p + 64); a3 = *(const short8*)(p4p + 96);
        tile2(A, b0, b1, b2, b3, rmaxc);
        lp = p4p;

        // chunk epilogue: reduce over n16, store 32 contiguous u16 (round-up)
        int cidx = qsplit * 16 + c;
        #pragma unroll
        for (int rf = 0; rf < 2; ++rf)
            #pragma unroll
            for (int r = 0; r < 4; ++r) {
                float v = rmaxc[rf][r];
                v = fmaxf(v, __shfl_xor(v, 1));
                v = fmaxf(v, __shfl_xor(v, 2));
                v = fmaxf(v, __shfl_xor(v, 4));
                v = fmaxf(v, __shfl_xor(v, 8));
                if (n16 == 0) {
                    unsigned int s = (ordered_bits(v) >> 16) + 1u;
                    if (s > 0xFFFFu) s = 0xFFFFu;
                    cm[(size_t)cidx * 4096 + rowbase + rf * 16 + quad * 4 + r]
                        = (unsigned short)s;
                }
                rmaxc[rf][r] = -1e30f;
            }
    }
}

// ---------- K4: per-row: rowmax over 1024 chunk maxes -> emit flagged pairs --
__global__ void k_select(const unsigned short* __restrict__ cm,
                         unsigned int* __restrict__ paircnt,
                         unsigned int* __restrict__ pairs) {
    int row = blockIdx.x * 128 + threadIdx.x;   // 0..4095 (32 blocks x 128)
    unsigned int m = 0;
    for (int c = 0; c < 1024; ++c) {
        unsigned int s = cm[(size_t)c * 4096 + row];
        m = max(m, s);
    }
    float vmax = from_ordered((m - 1u) << 16);  // <= true bf16 rowmax
    unsigned int thrU = ordered_bits(vmax - EPS_MARGIN) >> 16;  // trunc: conservative
    for (int c = 0; c < 1024; ++c) {
        unsigned int s = cm[(size_t)c * 4096 + row];
        if (s >= thrU) {
            unsigned int pos = atomicAdd(paircnt, 1u);
            if (pos < PAIR_CAP) pairs[pos] = ((unsigned int)row << 10) | (unsigned int)c;
        }
    }
}

// ---------- K5: exact fp32 re-rank of flagged 64-q chunks --------------------
// One block (256 thr) per pair, grid-stride. Thread t: q = q0 + t/4, k-quarter
// (t%4)*32; shfl-combine 4 lanes -> dot; packed max (lowest q on tie) -> best.
__global__ __launch_bounds__(256) void k_cexact(const float* __restrict__ pn,
                                                const float* __restrict__ queue,
                                                const unsigned int* __restrict__ paircnt,
                                                const unsigned int* __restrict__ pairs,
                                                unsigned long long* __restrict__ best) {
    __shared__ unsigned long long wmax[4];
    int tid = threadIdx.x, wv = tid >> 6, lane = tid & 63;
    unsigned int n = *paircnt; if (n > PAIR_CAP) n = PAIR_CAP;
    for (unsigned int p = blockIdx.x; p < n; p += gridDim.x) {
        unsigned int pr = pairs[p];
        unsigned int row = pr >> 10;
        unsigned int q = ((pr & 1023u) << 6) + (tid >> 2);
        int kq = (tid & 3) * 32;
        const float4* qs = (const float4*)(queue + (size_t)q * 128 + kq);
        const float4* ps = (const float4*)(pn + (size_t)row * 128 + kq);
        float s = 0.0f;
        #pragma unroll
        for (int j = 0; j < 8; ++j) {
            float4 x = ps[j], y = qs[j];
            s += x.x * y.x + x.y * y.y + x.z * y.z + x.w * y.w;
        }
        s += __shfl_xor(s, 1);
        s += __shfl_xor(s, 2);          // all 4 lanes of the group hold full dot
        unsigned long long pk = ((unsigned long long)ordered_bits(s) << 32)
                              | (unsigned long long)(unsigned int)(~q);
        #pragma unroll
        for (int o = 32; o; o >>= 1) {
            unsigned long long o2 = __shfl_xor(pk, o);
            if (o2 > pk) pk = o2;
        }
        if (lane == 0) wmax[wv] = pk;
        __syncthreads();
        if (tid == 0) {
            unsigned long long m0 = wmax[0];
            if (wmax[1] > m0) m0 = wmax[1];
            if (wmax[2] > m0) m0 = wmax[2];
            if (wmax[3] > m0) m0 = wmax[3];
            atomicMax(&best[row], m0);
        }
        __syncthreads();
    }
}

// ---------- K6: gather nn -> bf16 + EXACT fp32 diagonal ----------
__global__ void k_gather(const float* __restrict__ queue, const float* __restrict__ pn,
                         const unsigned long long* __restrict__ best,
                         short* __restrict__ nnb,
                         float* __restrict__ dg1, float* __restrict__ dg2) {
    int row = blockIdx.x;               // 0..4095
    int t = threadIdx.x;                // 0..63
    unsigned int idx = ~(unsigned int)(best[row] & 0xFFFFFFFFull);
    idx &= 0xFFFFu;
    float2 v = ((const float2*)(queue + (size_t)idx * 128))[t];
    unsigned int pk = (unsigned int)(unsigned short)bf_rne(v.x)
                    | ((unsigned int)(unsigned short)bf_rne(v.y) << 16);
    ((unsigned int*)(nnb + (size_t)row * 128))[t] = pk;
    // exact diag: nn[row] . partner_pn[row]
    const float* partner = (row < 2048) ? pn + (size_t)(2048 + row) * 128
                                        : pn + (size_t)(row - 2048) * 128;
    float2 p = ((const float2*)partner)[t];
    float d = v.x * p.x + v.y * p.y;
    #pragma unroll
    for (int o = 32; o; o >>= 1) d += __shfl_xor(d, o);
    if (t == 0) {
        if (row < 2048) dg1[row] = d;
        else dg2[row - 2048] = d;
    }
}

// ---------- K7: MFMA gemm+LSE partials: A(bf16) x B(bf16)^T -> exp sums ------
__global__ __launch_bounds__(256) void k_glse(const short* __restrict__ Ab,
                                              const short* __restrict__ Bb,
                                              float* __restrict__ rowsum,
                                              float* __restrict__ colsum) {
    int tid = threadIdx.x;
    int lane = tid & 63, wv = tid >> 6;
    int n16 = lane & 15, quad = lane >> 4;
    int rowbase = blockIdx.x * 64, colbase = blockIdx.y * 64;

    short8 A[4][4], B[4];
    #pragma unroll
    for (int rf = 0; rf < 4; ++rf) {
        const short* ap = Ab + (size_t)(rowbase + rf * 16 + n16) * 128 + quad * 8;
        #pragma unroll
        for (int kk = 0; kk < 4; ++kk) A[rf][kk] = *(const short8*)(ap + kk * 32);
    }
    const short* bp = Bb + (size_t)(colbase + wv * 16 + n16) * 128 + quad * 8;
    #pragma unroll
    for (int kk = 0; kk < 4; ++kk) B[kk] = *(const short8*)(bp + kk * 32);

    floatx4 acc[4];
    floatx4 zero = {0.0f, 0.0f, 0.0f, 0.0f};
    #pragma unroll
    for (int rf = 0; rf < 4; ++rf) acc[rf] = MFMA16(A[rf][0], B[0], zero);
    #pragma unroll
    for (int rf = 0; rf < 4; ++rf) acc[rf] = MFMA16(A[rf][1], B[1], acc[rf]);
    #pragma unroll
    for (int rf = 0; rf < 4; ++rf) acc[rf] = MFMA16(A[rf][2], B[2], acc[rf]);
    #pragma unroll
    for (int rf = 0; rf < 4; ++rf) acc[rf] = MFMA16(A[rf][3], B[3], acc[rf]);

    float e[4][4], csum = 0.0f;
    #pragma unroll
    for (int rf = 0; rf < 4; ++rf)
        #pragma unroll
        for (int r = 0; r < 4; ++r) {
            e[rf][r] = __expf(acc[rf][r] * SCALE - 10.0f);
            csum += e[rf][r];
        }
    #pragma unroll
    for (int rf = 0; rf < 4; ++rf)
        #pragma unroll
        for (int r = 0; r < 4; ++r) {
            float v = e[rf][r];
            v += __shfl_xor(v, 1);
            v += __shfl_xor(v, 2);
            v += __shfl_xor(v, 4);
            v += __shfl_xor(v, 8);
            if (n16 == 0)
                atomicAdd(&rowsum[rowbase + rf * 16 + quad * 4 + r], v);
        }
    csum += __shfl_xor(csum, 16);
    csum += __shfl_xor(csum, 32);
    if (quad == 0)
        atomicAdd(&colsum[colbase + wv * 16 + n16], csum);
}

// ---------- K8: final loss ----------
__global__ void k_final(const float* __restrict__ sums,
                        const float* __restrict__ dg1, const float* __restrict__ dg2,
                        float* __restrict__ out) {
    int idx = blockIdx.x * 256 + threadIdx.x;    // 0..8191
    int seg = idx >> 11, r = idx & 2047;
    float s = sums[seg * 2048 + r];
    float d = (seg < 2) ? dg1[r] : dg2[r];
    out[idx] = 10.0f + logf(s) - d * SCALE;
}

extern "C" void kernel_launch(void* const* d_in, const int* in_sizes, int n_in,
                              void* d_out, int out_size, void* d_ws, size_t ws_size,
                              hipStream_t stream) {
    const float* p1    = (const float*)d_in[0];   // [2048,128]
    const float* p2    = (const float*)d_in[1];   // [2048,128]
    const float* queue = (const float*)d_in[2];   // [65536,128]
    float* out = (float*)d_out;                   // [8192]

    char* w = (char*)d_ws;                        // footprint ~28.4 MiB (r8 proved OK)
    float* pn  = (float*)w;                               // 2 MB  fp32 [4096,128]
    short* nnb = (short*)(w + (2u << 20));                // 1 MB  bf16 [4096,128]
    short* qb  = (short*)(w + (3u << 20));                // 16 MB bf16 [65536,128]
    short* pnb = (short*)(w + (19u << 20));               // 1 MB  bf16 [4096,128]
    unsigned short* cm = (unsigned short*)(w + (20u << 20)); // 8 MB u16 [1024 chunks][4096 rows]
    char* b2 = w + (28u << 20);
    unsigned long long* best = (unsigned long long*)b2;             // 32 KB
    unsigned int* paircnt = (unsigned int*)(b2 + (32u << 10));      // 256 B
    unsigned int* pairs = (unsigned int*)(b2 + (33u << 10));        // 128 KB
    float* sums = (float*)(b2 + (161u << 10));                      // 32 KB
    float* dg1  = sums + 8192;                                      // 8 KB
    float* dg2  = dg1 + 2048;                                       // 8 KB

    k_prep<<<4096, 64, 0, stream>>>(p1, p2, pn, pnb, best, paircnt, sums);
    k_qcvt<<<4096, 256, 0, stream>>>(queue, qb);
    k_screen<<<2048, 256, 0, stream>>>(pnb, qb, cm);
    k_select<<<32, 128, 0, stream>>>(cm, paircnt, pairs);
    k_cexact<<<2048, 256, 0, stream>>>(pn, queue, paircnt, pairs, best);
    k_gather<<<4096, 64, 0, stream>>>(queue, pn, best, nnb, dg1, dg2);

    // M1 = nn1 @ p2n^T : rows -> loss[0..2047], cols -> loss[2048..4095]
    k_glse<<<dim3(32, 32), 256, 0, stream>>>(nnb, pnb + 2048 * 128,
                                             sums, sums + 2048);
    // M2 = nn2 @ p1n^T : rows -> loss[4096..6143], cols -> loss[6144..8191]
    k_glse<<<dim3(32, 32), 256, 0, stream>>>(nnb + 2048 * 128, pnb,
                                             sums + 4096, sums + 6144);
    k_final<<<32, 256, 0, stream>>>(sums, dg1, dg2, out);
}

// Round 11
// 298.605 us; speedup vs baseline: 2.2230x; 2.2230x over previous
//
#include <hip/hip_runtime.h>

#define SCALE 10.0f           // 1 / TEMPERATURE
#define EPS_MARGIN 0.008f     // 2 * (bf16 unit-dot hard error bound)
#define CAND_CAP 16384

typedef __attribute__((ext_vector_type(8))) short short8;
typedef __attribute__((ext_vector_type(4))) float floatx4;

#define MFMA16(a, b, c) __builtin_amdgcn_mfma_f32_16x16x32_bf16((a), (b), (c), 0, 0, 0)

// ---------- helpers ----------
__device__ __forceinline__ unsigned int ordered_bits(float f) {
    unsigned int b = __float_as_uint(f);
    return (b & 0x80000000u) ? ~b : (b | 0x80000000u);
}
__device__ __forceinline__ float from_ordered(unsigned int u) {
    return __uint_as_float((u & 0x80000000u) ? (u ^ 0x80000000u) : ~u);
}
__device__ __forceinline__ short bf_rne(float x) {   // fp32 -> bf16 bits, RNE
    unsigned int u = __float_as_uint(x);
    return (short)((u + 0x7FFFu + ((u >> 16) & 1u)) >> 16);
}

// ---------- K1: l2-normalize p1,p2 -> pn fp32 + pnb bf16; init state --------
__global__ void k_prep(const float* __restrict__ p1, const float* __restrict__ p2,
                       float* __restrict__ pn, short* __restrict__ pnb,
                       unsigned int* __restrict__ mbest,
                       unsigned long long* __restrict__ best, unsigned int* __restrict__ cnt,
                       float* __restrict__ sums) {
    int row = blockIdx.x;               // 0..4095
    int t = threadIdx.x;                // 0..63
    const float* src = (row < 2048) ? (p1 + (size_t)row * 128)
                                    : (p2 + (size_t)(row - 2048) * 128);
    float2 v = ((const float2*)src)[t];
    float ss = v.x * v.x + v.y * v.y;
    #pragma unroll
    for (int o = 32; o; o >>= 1) ss += __shfl_xor(ss, o);
    float inv = 1.0f / sqrtf(ss);
    float2 o2; o2.x = v.x * inv; o2.y = v.y * inv;
    ((float2*)(pn + (size_t)row * 128))[t] = o2;
    unsigned int pk = (unsigned int)(unsigned short)bf_rne(o2.x)
                    | ((unsigned int)(unsigned short)bf_rne(o2.y) << 16);
    ((unsigned int*)(pnb + (size_t)row * 128))[t] = pk;
    if (t == 0) { mbest[row] = 0u; best[row] = 0ULL; if (row == 0) *cnt = 0u; }
    if (row < 128) sums[row * 64 + t] = 0.0f;
}

// ---------- K2: queue fp32 -> qb bf16 ----------
__global__ void k_qcvt(const float* __restrict__ queue, short* __restrict__ qb) {
    size_t i = ((size_t)blockIdx.x * 256 + threadIdx.x) * 8;
    float4 f0 = *(const float4*)(queue + i);
    float4 f1 = *(const float4*)(queue + i + 4);
    short8 o;
    o[0] = bf_rne(f0.x); o[1] = bf_rne(f0.y); o[2] = bf_rne(f0.z); o[3] = bf_rne(f0.w);
    o[4] = bf_rne(f1.x); o[5] = bf_rne(f1.y); o[6] = bf_rne(f1.z); o[7] = bf_rne(f1.w);
    *(short8*)(qb + i) = o;
}

// ---------- screen compute step: 16-q tile, k-outer / rf-inner (8-way ILP) ---
template <int MODE>
__device__ __forceinline__ void screen_tile(const short8 A[8][4],
                                            short8 b0, short8 b1, short8 b2, short8 b3,
                                            float rmax[8][4], const float thr[8][4],
                                            int qtile, int rowbase, int quad, int n16,
                                            unsigned int* cnt, unsigned long long* cand) {
    floatx4 acc[8];
    floatx4 zero = {0.0f, 0.0f, 0.0f, 0.0f};
    #pragma unroll
    for (int rf = 0; rf < 8; ++rf) acc[rf] = MFMA16(A[rf][0], b0, zero);
    #pragma unroll
    for (int rf = 0; rf < 8; ++rf) acc[rf] = MFMA16(A[rf][1], b1, acc[rf]);
    #pragma unroll
    for (int rf = 0; rf < 8; ++rf) acc[rf] = MFMA16(A[rf][2], b2, acc[rf]);
    #pragma unroll
    for (int rf = 0; rf < 8; ++rf) acc[rf] = MFMA16(A[rf][3], b3, acc[rf]);

    if (MODE == 0) {
        #pragma unroll
        for (int rf = 0; rf < 8; ++rf)
            #pragma unroll
            for (int r = 0; r < 4; ++r) rmax[rf][r] = fmaxf(rmax[rf][r], acc[rf][r]);
    } else {
        float any = -1.0f;
        #pragma unroll
        for (int rf = 0; rf < 8; ++rf)
            #pragma unroll
            for (int r = 0; r < 4; ++r) any = fmaxf(any, acc[rf][r] - thr[rf][r]);
        if (__any(any > 0.0f)) {        // rare path
            #pragma unroll
            for (int rf = 0; rf < 8; ++rf)
                #pragma unroll
                for (int r = 0; r < 4; ++r) {
                    if (acc[rf][r] > thr[rf][r]) {
                        unsigned int pos = atomicAdd(cnt, 1u);
                        if (pos < CAND_CAP)
                            cand[pos] = ((unsigned long long)(unsigned int)(rowbase + rf * 16 + quad * 4 + r) << 32)
                                      | (unsigned int)(qtile * 16 + n16);
                    }
                }
        }
    }
}

// ---------- K3/K4: bf16 MFMA screen, two passes (r7 config: 89 us each) ------
// Block = 4 waves x SAME 1024-q strip (B shared via L1/L2), wave owns 128 rows
// (A in 128 VGPRs). Grid 512 = 8 rowblocks x 64 qsplits, XCD-swizzled so each
// XCD touches 8 qsplits = 2 MB of qb (L2-resident). 2x-unrolled K-loop with
// two B register sets; barrier every 16 tiles keeps waves converged (L1 share).
template <int MODE>
__global__ __launch_bounds__(256, 2) void k_screen(const short* __restrict__ pnb,
                                                   const short* __restrict__ qb,
                                                   unsigned int* __restrict__ mbest,
                                                   unsigned int* __restrict__ cnt,
                                                   unsigned long long* __restrict__ cand) {
    int tid = threadIdx.x;
    int lane = tid & 63, wv = tid >> 6;
    int n16 = lane & 15, quad = lane >> 4;

    int id = blockIdx.x;                // 0..511
    int xcd = id & 7;
    int g = id >> 3;                    // 0..63
    int rowblk = g & 7;
    int qsub = g >> 3;
    int qsplit = xcd * 8 + qsub;
    int rowbase = rowblk * 512 + wv * 128;
    int qstart = qsplit * 1024;

    short8 A[8][4];
    #pragma unroll
    for (int rf = 0; rf < 8; ++rf) {
        const short* ap = pnb + (size_t)(rowbase + rf * 16 + n16) * 128 + quad * 8;
        #pragma unroll
        for (int kk = 0; kk < 4; ++kk)
            A[rf][kk] = *(const short8*)(ap + kk * 32);
    }

    float rmax[8][4], thr[8][4];
    #pragma unroll
    for (int rf = 0; rf < 8; ++rf)
        #pragma unroll
        for (int r = 0; r < 4; ++r) {
            if (MODE == 0) rmax[rf][r] = -1e30f;
            else thr[rf][r] = from_ordered(mbest[rowbase + rf * 16 + quad * 4 + r]) - EPS_MARGIN;
        }

    const short* lp = qb + (size_t)(qstart + n16) * 128 + quad * 8;
    short8 a0 = *(const short8*)(lp), a1 = *(const short8*)(lp + 32),
           a2 = *(const short8*)(lp + 64), a3 = *(const short8*)(lp + 96);

    for (int t = 0; t < 64; t += 2) {
        if ((t & 15) == 0) __syncthreads();
        const short* p1p = lp + 2048;
        short8 b0 = *(const short8*)(p1p), b1 = *(const short8*)(p1p + 32),
               b2 = *(const short8*)(p1p + 64), b3 = *(const short8*)(p1p + 96);
        screen_tile<MODE>(A, a0, a1, a2, a3, rmax, thr,
                          qstart / 16 + t, rowbase, quad, n16, cnt, cand);
        const short* p2p = lp + 4096;   // tail over-read lands in pnb (safe)
        a0 = *(const short8*)(p2p); a1 = *(const short8*)(p2p + 32);
        a2 = *(const short8*)(p2p + 64); a3 = *(const short8*)(p2p + 96);
        screen_tile<MODE>(A, b0, b1, b2, b3, rmax, thr,
                          qstart / 16 + t + 1, rowbase, quad, n16, cnt, cand);
        lp += 4096;
    }

    if (MODE == 0) {
        #pragma unroll
        for (int rf = 0; rf < 8; ++rf)
            #pragma unroll
            for (int r = 0; r < 4; ++r) {
                float v = rmax[rf][r];
                v = fmaxf(v, __shfl_xor(v, 1));
                v = fmaxf(v, __shfl_xor(v, 2));
                v = fmaxf(v, __shfl_xor(v, 4));
                v = fmaxf(v, __shfl_xor(v, 8));
                if (n16 == 0)
                    atomicMax(&mbest[rowbase + rf * 16 + quad * 4 + r], ordered_bits(v));
            }
    }
}

// ---------- K5: exact fp32 re-rank of candidates (one wave each) ----------
__global__ void k_rerank(const float* __restrict__ pn, const float* __restrict__ queue,
                         const unsigned int* __restrict__ cnt,
                         const unsigned long long* __restrict__ cand,
                         unsigned long long* __restrict__ best) {
    int widx = (blockIdx.x * 256 + threadIdx.x) >> 6;
    int lane = threadIdx.x & 63;
    unsigned int n = *cnt; if (n > CAND_CAP) n = CAND_CAP;
    if ((unsigned int)widx >= n) return;
    unsigned long long c = cand[widx];
    unsigned int row = (unsigned int)(c >> 32);
    unsigned int q = (unsigned int)c;
    float2 a = ((const float2*)(pn + (size_t)row * 128))[lane];
    float2 b = ((const float2*)(queue + (size_t)q * 128))[lane];
    float d = a.x * b.x + a.y * b.y;
    #pragma unroll
    for (int o = 32; o; o >>= 1) d += __shfl_xor(d, o);
    if (lane == 0) {
        unsigned long long pk = ((unsigned long long)ordered_bits(d) << 32)
                              | (unsigned long long)(unsigned int)(~q);
        atomicMax(&best[row], pk);
    }
}

// ---------- K6: gather nn -> bf16 + EXACT fp32 diagonal ----------
__global__ void k_gather(const float* __restrict__ queue, const float* __restrict__ pn,
                         const unsigned long long* __restrict__ best,
                         short* __restrict__ nnb,
                         float* __restrict__ dg1, float* __restrict__ dg2) {
    int row = blockIdx.x;               // 0..4095
    int t = threadIdx.x;                // 0..63
    unsigned int idx = ~(unsigned int)(best[row] & 0xFFFFFFFFull);
    idx &= 0xFFFFu;
    float2 v = ((const float2*)(queue + (size_t)idx * 128))[t];
    unsigned int pk = (unsigned int)(unsigned short)bf_rne(v.x)
                    | ((unsigned int)(unsigned short)bf_rne(v.y) << 16);
    ((unsigned int*)(nnb + (size_t)row * 128))[t] = pk;
    const float* partner = (row < 2048) ? pn + (size_t)(2048 + row) * 128
                                        : pn + (size_t)(row - 2048) * 128;
    float2 p = ((const float2*)partner)[t];
    float d = v.x * p.x + v.y * p.y;
    #pragma unroll
    for (int o = 32; o; o >>= 1) d += __shfl_xor(d, o);
    if (t == 0) {
        if (row < 2048) dg1[row] = d;
        else dg2[row - 2048] = d;
    }
}

// ---------- K7: MFMA gemm+LSE partials: A(bf16) x B(bf16)^T -> exp sums ------
// Grid (32,32), 4 waves; wave owns cols colbase + wv*16. Fixed-shift LSE.
__global__ __launch_bounds__(256) void k_glse(const short* __restrict__ Ab,
                                              const short* __restrict__ Bb,
                                              float* __restrict__ rowsum,
                                              float* __restrict__ colsum) {
    int tid = threadIdx.x;
    int lane = tid & 63, wv = tid >> 6;
    int n16 = lane & 15, quad = lane >> 4;
    int rowbase = blockIdx.x * 64, colbase = blockIdx.y * 64;

    short8 A[4][4], B[4];
    #pragma unroll
    for (int rf = 0; rf < 4; ++rf) {
        const short* ap = Ab + (size_t)(rowbase + rf * 16 + n16) * 128 + quad * 8;
        #pragma unroll
        for (int kk = 0; kk < 4; ++kk) A[rf][kk] = *(const short8*)(ap + kk * 32);
    }
    const short* bp = Bb + (size_t)(colbase + wv * 16 + n16) * 128 + quad * 8;
    #pragma unroll
    for (int kk = 0; kk < 4; ++kk) B[kk] = *(const short8*)(bp + kk * 32);

    floatx4 acc[4];
    floatx4 zero = {0.0f, 0.0f, 0.0f, 0.0f};
    #pragma unroll
    for (int rf = 0; rf < 4; ++rf) acc[rf] = MFMA16(A[rf][0], B[0], zero);
    #pragma unroll
    for (int rf = 0; rf < 4; ++rf) acc[rf] = MFMA16(A[rf][1], B[1], acc[rf]);
    #pragma unroll
    for (int rf = 0; rf < 4; ++rf) acc[rf] = MFMA16(A[rf][2], B[2], acc[rf]);
    #pragma unroll
    for (int rf = 0; rf < 4; ++rf) acc[rf] = MFMA16(A[rf][3], B[3], acc[rf]);

    float e[4][4], csum = 0.0f;
    #pragma unroll
    for (int rf = 0; rf < 4; ++rf)
        #pragma unroll
        for (int r = 0; r < 4; ++r) {
            e[rf][r] = __expf(acc[rf][r] * SCALE - 10.0f);
            csum += e[rf][r];
        }
    #pragma unroll
    for (int rf = 0; rf < 4; ++rf)
        #pragma unroll
        for (int r = 0; r < 4; ++r) {
            float v = e[rf][r];
            v += __shfl_xor(v, 1);
            v += __shfl_xor(v, 2);
            v += __shfl_xor(v, 4);
            v += __shfl_xor(v, 8);
            if (n16 == 0)
                atomicAdd(&rowsum[rowbase + rf * 16 + quad * 4 + r], v);
        }
    csum += __shfl_xor(csum, 16);
    csum += __shfl_xor(csum, 32);
    if (quad == 0)
        atomicAdd(&colsum[colbase + wv * 16 + n16], csum);
}

// ---------- K8: final loss ----------
__global__ void k_final(const float* __restrict__ sums,
                        const float* __restrict__ dg1, const float* __restrict__ dg2,
                        float* __restrict__ out) {
    int idx = blockIdx.x * 256 + threadIdx.x;    // 0..8191
    int seg = idx >> 11, r = idx & 2047;
    float s = sums[seg * 2048 + r];
    float d = (seg < 2) ? dg1[r] : dg2[r];
    out[idx] = 10.0f + logf(s) - d * SCALE;
}

extern "C" void kernel_launch(void* const* d_in, const int* in_sizes, int n_in,
                              void* d_out, int out_size, void* d_ws, size_t ws_size,
                              hipStream_t stream) {
    const float* p1    = (const float*)d_in[0];   // [2048,128]
    const float* p2    = (const float*)d_in[1];   // [2048,128]
    const float* queue = (const float*)d_in[2];   // [65536,128]
    float* out = (float*)d_out;                   // [8192]

    char* w = (char*)d_ws;                        // footprint ~20.8 MiB
    float* pn  = (float*)w;                               // 2 MB  fp32 [4096,128]
    short* nnb = (short*)(w + (2u << 20));                // 1 MB  bf16 [4096,128]
    short* qb  = (short*)(w + (3u << 20));                // 16 MB bf16 [65536,128]
    short* pnb = (short*)(w + (19u << 20));               // 1 MB  bf16 [4096,128]
    char* b2 = w + (20u << 20);
    unsigned int* mbest = (unsigned int*)b2;                        // 16 KB
    unsigned long long* best = (unsigned long long*)(b2 + (16u << 10)); // 32 KB
    unsigned int* cnt = (unsigned int*)(b2 + (48u << 10));          // 256 B
    unsigned long long* cand = (unsigned long long*)(b2 + (64u << 10)); // 128 KB
    float* sums = (float*)(b2 + (192u << 10));                      // 32 KB
    float* dg1  = sums + 8192;                                      // 8 KB
    float* dg2  = dg1 + 2048;                                       // 8 KB

    k_prep<<<4096, 64, 0, stream>>>(p1, p2, pn, pnb, mbest, best, cnt, sums);
    k_qcvt<<<4096, 256, 0, stream>>>(queue, qb);
    k_screen<0><<<512, 256, 0, stream>>>(pnb, qb, mbest, cnt, cand);
    k_screen<1><<<512, 256, 0, stream>>>(pnb, qb, mbest, cnt, cand);
    k_rerank<<<4096, 256, 0, stream>>>(pn, queue, cnt, cand, best);
    k_gather<<<4096, 64, 0, stream>>>(queue, pn, best, nnb, dg1, dg2);

    // M1 = nn1 @ p2n^T : rows -> loss[0..2047], cols -> loss[2048..4095]
    k_glse<<<dim3(32, 32), 256, 0, stream>>>(nnb, pnb + 2048 * 128,
                                             sums, sums + 2048);
    // M2 = nn2 @ p1n^T : rows -> loss[4096..6143], cols -> loss[6144..8191]
    k_glse<<<dim3(32, 32), 256, 0, stream>>>(nnb + 2048 * 128, pnb,
                                             sums + 4096, sums + 6144);
    k_final<<<32, 256, 0, stream>>>(sums, dg1, dg2, out);
}